// Round 12
// baseline (184.375 us; speedup 1.0000x reference)
//
#include <hip/hip_runtime.h>

typedef unsigned short u16;
typedef unsigned int u32;
typedef u16 u16x4 __attribute__((ext_vector_type(4)));
typedef u16 u16x8 __attribute__((ext_vector_type(8)));
typedef u32 u32x4 __attribute__((ext_vector_type(4)));
typedef __bf16 bf16x8 __attribute__((ext_vector_type(8)));
typedef float floatx4 __attribute__((ext_vector_type(4)));
typedef float floatx16 __attribute__((ext_vector_type(16)));

#define N_EMBD 1024
#define N_HEAD 16
#define HEAD_DIM 64
#define SEQ 2048
#define BATCH 2
#define M_ROWS (BATCH * SEQ)  // 4096

typedef __attribute__((address_space(1))) const unsigned char ga_t;
typedef __attribute__((address_space(3))) unsigned char la_t;

#if __has_builtin(__builtin_amdgcn_exp2f)
#define EXP2(x) __builtin_amdgcn_exp2f(x)
#else
#define EXP2(x) exp2f(x)
#endif

// native gfx950 f32->bf16 (RNE), 1 instr
__device__ __forceinline__ u16 cvt_bf16(float f) {
  return __builtin_bit_cast(u16, (__bf16)f);
}
__device__ __forceinline__ u32 pk2(float a, float b) {
  return (u32)cvt_bf16(a) | ((u32)cvt_bf16(b) << 16);
}

// ======== prep: convert x (blocks 0..2047) + transpose both weights ========
__global__ __launch_bounds__(256) void prep(const float* __restrict__ x,
                                            u16* __restrict__ xb,
                                            const float* __restrict__ wa,
                                            const float* __restrict__ wp,
                                            u16* __restrict__ outa,
                                            u16* __restrict__ outp) {
  const int bid = blockIdx.x;
  if (bid < 2048) {  // convert_x
    const long i = ((long)bid * 256 + threadIdx.x) * 8;
    const float4 f0 = *(const float4*)&x[i];
    const float4 f1 = *(const float4*)&x[i + 4];
    u16x8 p;
    p[0] = cvt_bf16(f0.x); p[1] = cvt_bf16(f0.y);
    p[2] = cvt_bf16(f0.z); p[3] = cvt_bf16(f0.w);
    p[4] = cvt_bf16(f1.x); p[5] = cvt_bf16(f1.y);
    p[6] = cvt_bf16(f1.z); p[7] = cvt_bf16(f1.w);
    *(u16x8*)&xb[i] = p;
    return;
  }
  // transpose: linearized (gx 0..127, gy 0..31); gx<96: w_attn, else w_proj
  __shared__ u16 tile[32][33];
  const int t = bid - 2048;
  const int gx = t & 127;
  const int gy = t >> 7;
  const int R = N_EMBD;
  const float* in;
  u16* out;
  int C, bx;
  if (gx < 96) {
    in = wa; out = outa; C = 3 * N_EMBD; bx = gx * 32;
  } else {
    in = wp; out = outp; C = N_EMBD; bx = (gx - 96) * 32;
  }
  const int by = gy * 32;
  const int tx = threadIdx.x & 31;
  const int ty = threadIdx.x >> 5;
#pragma unroll
  for (int j = 0; j < 32; j += 8)
    tile[ty + j][tx] = cvt_bf16(in[(long)(by + ty + j) * C + bx + tx]);
  __syncthreads();
#pragma unroll
  for (int j = 0; j < 32; j += 8)
    out[(long)(bx + ty + j) * R + by + tx] = tile[tx][ty + j];
}

// ======== gemm_qkv — 128x192 tile, BK=64, 8 waves, reg-pipelined ========
// (unchanged from round 10 — verified)
#define GBK 64

__device__ __forceinline__ void stage192(const u16* __restrict__ A,
                                         const u16* __restrict__ Bt, int bm,
                                         int bn, int kt, int tid, u16* as,
                                         u16* bs) {
#pragma unroll
  for (int i = 0; i < 2; ++i) {  // A: 128 rows x 8 slots = 1024 chunks
    const int p = tid + 512 * i;
    const int row = p >> 3;              // 0..127
    const int sl = (p & 7) ^ (row & 7);  // inverse-swizzled 16B source slot
    const int wb = (i * 512 + (tid & 448)) * 8;  // wave-uniform dest (u16)
    __builtin_amdgcn_global_load_lds(
        (ga_t*)&A[(long)(bm + row) * N_EMBD + kt + sl * 8], (la_t*)&as[wb], 16,
        0, 0);
  }
#pragma unroll
  for (int i = 0; i < 3; ++i) {  // B: 192 rows x 8 slots = 1536 chunks
    const int p = tid + 512 * i;
    const int row = p >> 3;              // 0..191
    const int sl = (p & 7) ^ (row & 7);
    const int wb = (i * 512 + (tid & 448)) * 8;
    __builtin_amdgcn_global_load_lds(
        (ga_t*)&Bt[(long)(bn + row) * N_EMBD + kt + sl * 8], (la_t*)&bs[wb], 16,
        0, 0);
  }
}

__global__ __launch_bounds__(512, 4) void gemm_qkv(
    const u16* __restrict__ A, const u16* __restrict__ Bt,
    const float* __restrict__ bias, u16* __restrict__ qo, u16* __restrict__ ko,
    u16* __restrict__ vo) {
  extern __shared__ u16 smem[];
  u16* As = smem;                 // [2][128*64]
  u16* Bs = smem + 2 * 128 * 64;  // [2][192*64]
  const int tid = threadIdx.x;

  // bijective XCD swizzle (nwg = 512)
  const int nx = gridDim.x;  // 16
  const int nwg = nx * gridDim.y;
  int lin = blockIdx.y * nx + blockIdx.x;
  lin = (lin & 7) * (nwg >> 3) + (lin >> 3);
  const int bm = (lin / nx) * 128;
  const int bn = (lin % nx) * 192;

  const int w = tid >> 6;        // 0..7
  const int l = tid & 63;
  const int wm = (w >> 2) * 64;  // 2 M-rows of waves
  const int wn = (w & 3) * 48;   // 4 N-cols of waves (48 = mult of 16)
  const int m16 = l & 15;
  const int quad = l >> 4;
  const int rsw = m16 & 7;  // read-side XOR (frag row&7 == m16&7)

  floatx4 acc[4][3];
#pragma unroll
  for (int i = 0; i < 4; ++i)
#pragma unroll
    for (int j = 0; j < 3; ++j) acc[i][j] = (floatx4){0.f, 0.f, 0.f, 0.f};

  // prologue: tiles 0,1 in flight (5 loads each); wait tile 0
  stage192(A, Bt, bm, bn, 0, tid, As, Bs);
  stage192(A, Bt, bm, bn, GBK, tid, As + 128 * 64, Bs + 192 * 64);
  asm volatile("s_waitcnt vmcnt(5)" ::: "memory");
  __builtin_amdgcn_s_barrier();

  for (int kt = 0; kt < 16; ++kt) {
    u16* as = As + (kt & 1) * (128 * 64);
    u16* bs = Bs + (kt & 1) * (192 * 64);

    // all fragments of tile kt -> registers (14 x ds_read_b128)
    bf16x8 af[4][2], bf[3][2];
#pragma unroll
    for (int i = 0; i < 4; ++i)
#pragma unroll
      for (int kk = 0; kk < 2; ++kk)
        af[i][kk] = __builtin_bit_cast(
            bf16x8, *(const u16x8*)&as[(wm + i * 16 + m16) * 64 +
                                       (((kk * 4 + quad) ^ rsw) * 8)]);
#pragma unroll
    for (int j = 0; j < 3; ++j)
#pragma unroll
      for (int kk = 0; kk < 2; ++kk)
        bf[j][kk] = __builtin_bit_cast(
            bf16x8, *(const u16x8*)&bs[(wn + j * 16 + m16) * 64 +
                                       (((kk * 4 + quad) ^ rsw) * 8)]);
    asm volatile("s_waitcnt lgkmcnt(0)" ::: "memory");
    __builtin_amdgcn_s_barrier();  // all waves done READING this buffer

    if (kt + 2 < 16) {
      stage192(A, Bt, bm, bn, (kt + 2) * GBK, tid, as, bs);  // freed buffer
      asm volatile("s_waitcnt vmcnt(5)" ::: "memory");  // own kt+1 loads done
    } else {
      asm volatile("s_waitcnt vmcnt(0)" ::: "memory");
    }
    __builtin_amdgcn_s_barrier();  // tile kt+1 visible to every wave

    __builtin_amdgcn_s_setprio(1);
#pragma unroll
    for (int kk = 0; kk < 2; ++kk)  // kk outermost: no dependent MFMA pairs
#pragma unroll
      for (int i = 0; i < 4; ++i)
#pragma unroll
        for (int j = 0; j < 3; ++j)
          acc[i][j] = __builtin_amdgcn_mfma_f32_16x16x32_bf16(
              af[i][kk], bf[j][kk], acc[i][j], 0, 0, 0);
    __builtin_amdgcn_s_setprio(0);
  }

  // epilogue: scatter q/k (bf16 [B,H,T,D]) and vT ([B,H,D,T])
#pragma unroll
  for (int i = 0; i < 4; ++i) {
#pragma unroll
    for (int j = 0; j < 3; ++j) {
      const int col = bn + wn + j * 16 + m16;
      const float bv = bias[col];
      const int which = col >> 10;  // 0=q 1=k 2=v (uniform: 16-col frag
      const int cc = col & 1023;    //  is 16-aligned, never crosses 64)
      const int h = cc >> 6;
      const int dd = cc & 63;
      const int row0 = bm + wm + i * 16 + quad * 4;
      const int b = row0 >> 11;
      const int t0 = row0 & 2047;
      if (which == 2) {
        u16x4 pk;
#pragma unroll
        for (int r = 0; r < 4; ++r) pk[r] = cvt_bf16(acc[i][j][r] + bv);
        *(u16x4*)&vo[(((long)(b * N_HEAD + h)) * HEAD_DIM + dd) * SEQ + t0] =
            pk;
      } else {
        u16* dst = (which == 0) ? qo : ko;
#pragma unroll
        for (int r = 0; r < 4; ++r)
          dst[(((long)(b * N_HEAD + h)) * SEQ + t0 + r) * HEAD_DIM + dd] =
              cvt_bf16(acc[i][j][r] + bv);
      }
    }
  }
}

// ======== gemm_proj — 128x64 tile, BK=64, 4 waves, reg-pipelined ========
// (unchanged from round 11 — verified)
#define PBK 64

__device__ __forceinline__ void stage_proj(const u16* __restrict__ A,
                                           const u16* __restrict__ Bt, int bm,
                                           int bn, int kt, int tid, u16* as,
                                           u16* bs) {
  const int head = kt >> 6;  // kt is a multiple of 64
#pragma unroll
  for (int i = 0; i < 4; ++i) {  // A: 128 rows x 8 slots = 1024 chunks
    const int p = tid + 256 * i;
    const int row = p >> 3;              // 0..127
    const int sl = (p & 7) ^ (row & 7);  // inverse-swizzled 16B source slot
    const int wb = (i * 256 + (tid & 192)) * 8;  // wave-uniform dest (u16)
    const int m = bm + row;
    const int b = m >> 11, t = m & 2047;
    __builtin_amdgcn_global_load_lds(
        (ga_t*)&A[(((long)(b * N_HEAD + head)) * SEQ + t) * HEAD_DIM + sl * 8],
        (la_t*)&as[wb], 16, 0, 0);
  }
#pragma unroll
  for (int i = 0; i < 2; ++i) {  // B: 64 rows x 8 slots = 512 chunks
    const int p = tid + 256 * i;
    const int row = p >> 3;  // 0..63
    const int sl = (p & 7) ^ (row & 7);
    const int wb = (i * 256 + (tid & 192)) * 8;
    __builtin_amdgcn_global_load_lds(
        (ga_t*)&Bt[(long)(bn + row) * N_EMBD + kt + sl * 8], (la_t*)&bs[wb], 16,
        0, 0);
  }
}

__global__ __launch_bounds__(256) void gemm_proj(const u16* __restrict__ A,
                                                 const u16* __restrict__ Bt,
                                                 const float* __restrict__ bias,
                                                 float* __restrict__ out) {
  __shared__ u16 As[2][128 * 64];  // 32 KB
  __shared__ u16 Bs[2][64 * 64];   // 16 KB
  const int tid = threadIdx.x;

  // bijective XCD swizzle (nwg = 512)
  const int nx = gridDim.x;  // 16
  const int nwg = nx * gridDim.y;
  int lin = blockIdx.y * nx + blockIdx.x;
  lin = (lin & 7) * (nwg >> 3) + (lin >> 3);
  const int bm = (lin / nx) * 128;
  const int bn = (lin % nx) * 64;

  const int w = tid >> 6;        // 0..3
  const int l = tid & 63;
  const int wm = (w >> 1) * 64;  // {0,64}
  const int wn = (w & 1) * 32;   // {0,32}
  const int m16 = l & 15;
  const int quad = l >> 4;
  const int rsw = m16 & 7;

  floatx4 acc[4][2];
#pragma unroll
  for (int i = 0; i < 4; ++i)
#pragma unroll
    for (int j = 0; j < 2; ++j) acc[i][j] = (floatx4){0.f, 0.f, 0.f, 0.f};

  // prologue: tiles 0,1 in flight (6 loads each); wait tile 0
  stage_proj(A, Bt, bm, bn, 0, tid, As[0], Bs[0]);
  stage_proj(A, Bt, bm, bn, PBK, tid, As[1], Bs[1]);
  asm volatile("s_waitcnt vmcnt(6)" ::: "memory");
  __builtin_amdgcn_s_barrier();

  for (int kt = 0; kt < 16; ++kt) {
    u16* as = As[kt & 1];
    u16* bs = Bs[kt & 1];

    bf16x8 af[4][2], bf[2][2];
#pragma unroll
    for (int i = 0; i < 4; ++i)
#pragma unroll
      for (int kk = 0; kk < 2; ++kk)
        af[i][kk] = __builtin_bit_cast(
            bf16x8, *(const u16x8*)&as[(wm + i * 16 + m16) * 64 +
                                       (((kk * 4 + quad) ^ rsw) * 8)]);
#pragma unroll
    for (int j = 0; j < 2; ++j)
#pragma unroll
      for (int kk = 0; kk < 2; ++kk)
        bf[j][kk] = __builtin_bit_cast(
            bf16x8, *(const u16x8*)&bs[(wn + j * 16 + m16) * 64 +
                                       (((kk * 4 + quad) ^ rsw) * 8)]);
    asm volatile("s_waitcnt lgkmcnt(0)" ::: "memory");
    __builtin_amdgcn_s_barrier();  // all waves done READING this buffer

    if (kt + 2 < 16) {
      stage_proj(A, Bt, bm, bn, (kt + 2) * PBK, tid, as, bs);
      asm volatile("s_waitcnt vmcnt(6)" ::: "memory");  // own kt+1 loads done
    } else {
      asm volatile("s_waitcnt vmcnt(0)" ::: "memory");
    }
    __builtin_amdgcn_s_barrier();  // tile kt+1 visible to every wave

    __builtin_amdgcn_s_setprio(1);
#pragma unroll
    for (int kk = 0; kk < 2; ++kk)
#pragma unroll
      for (int i = 0; i < 4; ++i)
#pragma unroll
        for (int j = 0; j < 2; ++j)
          acc[i][j] = __builtin_amdgcn_mfma_f32_16x16x32_bf16(
              af[i][kk], bf[j][kk], acc[i][j], 0, 0, 0);
    __builtin_amdgcn_s_setprio(0);
  }

  // epilogue: fp32 out + bias
#pragma unroll
  for (int i = 0; i < 4; ++i) {
#pragma unroll
    for (int j = 0; j < 2; ++j) {
      const int col = bn + wn + j * 16 + m16;
      const float bv = bias[col];
#pragma unroll
      for (int r = 0; r < 4; ++r) {
        const int row = bm + wm + i * 16 + quad * 4 + r;
        out[(long)row * N_EMBD + col] = acc[i][j][r] + bv;
      }
    }
  }
}

// ======== flash attention — swapped QK^T, 32x32 MFMA, P in registers =====
// 1024 blocks (32 q-tiles x 32 bh), 128 threads (2 warps x 32 q-rows).
// Round-5 balanced CU mapping verbatim. K/V staging + swizzle + one-barrier
// double-buffer verbatim. LDS = Kl 16K + Vl 16K = 32K (Pl GONE).
//
// S^T = K . Q^T via mfma_32x32x16: lane (h=l>>5, q32=l&31) holds, for its
// q = qb + w*32 + q32, scores of 32 keys: key = kh*32 + (reg&3)+8*(reg>>2)
// + 4h (C/D map m74/m101). Row-max/sum are LANE-LOCAL (+1 shfl_xor(32)).
// P packs to bf16 u32-pairs in-register; the 8 partner-owned u32s arrive
// via shfl_xor(32); PV consumes them directly as the 32x32x16 B-operand:
//   B-frag for key-slice ks needs keys ks*16+8h+{0..7}: j=0..3 live in
//   h''=0 lanes at m=2ks'+h, j=4..7 in h''=1 (m = reg>>2, c = reg&3,
//   key = c+8m+4h''). Send pr[2ks'+(1-h)], receive partner's = pr[2ks'+h].
#define BQ 64
#define BKV 64
#define LOG2E 1.44269504f
#define NQT (SEQ / BQ)  // 32 q-tiles

__device__ __forceinline__ void stage_kv(const u16* __restrict__ K,
                                         const u16* __restrict__ Vt, long bh,
                                         int kt, int tid, u16* kl, u16* vl) {
#pragma unroll
  for (int i = 0; i < 4; ++i) {
    const int p = tid + 128 * i;
    const int row = p >> 3;                     // K: key   V: d
    const int slot = (p & 7) ^ (row & 7);       // swizzled 16B source slot
    const int wb = (i * 128 + (tid & 64)) * 8;  // wave-uniform dest (u16)
    __builtin_amdgcn_global_load_lds(
        (ga_t*)&K[(bh * SEQ + kt + row) * HEAD_DIM + slot * 8], (la_t*)&kl[wb],
        16, 0, 0);
    __builtin_amdgcn_global_load_lds(
        (ga_t*)&Vt[(bh * HEAD_DIM + row) * SEQ + kt + slot * 8], (la_t*)&vl[wb],
        16, 0, 0);
  }
}

__global__ __launch_bounds__(128, 2) void flash_attn(
    u16* __restrict__ Qy, const u16* __restrict__ K,
    const u16* __restrict__ Vt) {
  const int id = blockIdx.x;
  const int r = id >> 8;  // 0..3  (co-CU class = id & 255)
  const int c = id & 255;
  const int g = c >> 5;   // 0..7
  const long bh = c & 31;
  const int iq = (r == 0) ? (31 - g)
               : (r == 1) ? (16 + g)
               : (r == 2) ? (15 - g)
                          : g;
  const int tid = threadIdx.x;
  const int w = tid >> 6;  // 0..1
  const int l = tid & 63;
  const int q32 = l & 31;
  const int h = l >> 5;
  const int l7 = l & 7;

  __shared__ u16 Kl[2][BKV * 64];  // [buf][key][d]  linear, swizzled source
  __shared__ u16 Vl[2][64 * BKV];  // [buf][d][key]  linear, swizzled source

  const float SC = 0.125f * LOG2E;
  const int qb = iq * BQ;
  const int ntiles = iq + 1;
  const int qglob = qb + w * 32 + q32;

  // Q fragments: Q^T B-operand, qf[ds] = Q[qglob][ds*16 + h*8 + 0..7]
  bf16x8 qf[4];
  {
    const u16* qrow = Qy + (bh * SEQ + qglob) * HEAD_DIM;
#pragma unroll
    for (int ds = 0; ds < 4; ++ds)
      qf[ds] = __builtin_bit_cast(bf16x8, *(const u16x8*)&qrow[ds * 16 + h * 8]);
  }

  floatx16 Oacc[2];  // O^T[d][q]: d = dh*32 + (reg&3)+8*(reg>>2)+4h, q = q32
#pragma unroll
  for (int t = 0; t < 2; ++t)
#pragma unroll
    for (int e = 0; e < 16; ++e) Oacc[t][e] = 0.f;
  float mrow = -1e30f, lsum = 0.f;  // per-lane (own 32 keys); merged at end

  stage_kv(K, Vt, bh, 0, tid, Kl[0], Vl[0]);
  __syncthreads();

  for (int it = 0; it < ntiles; ++it) {
    const int buf = it & 1;
    const int kt = it * BKV;
    if (it + 1 < ntiles)
      stage_kv(K, Vt, bh, kt + BKV, tid, Kl[buf ^ 1], Vl[buf ^ 1]);

    // ---- K fragments + S^T = K Q^T ----
    bf16x8 kf[2][4];
#pragma unroll
    for (int kh = 0; kh < 2; ++kh) {
      const int krow = kh * 32 + q32;  // krow&7 == l7
#pragma unroll
      for (int ds = 0; ds < 4; ++ds)
        kf[kh][ds] = __builtin_bit_cast(
            bf16x8,
            *(const u16x8*)&Kl[buf][krow * 64 + (((ds * 2 + h) ^ l7) * 8)]);
    }
    floatx16 s[2];
#pragma unroll
    for (int kh = 0; kh < 2; ++kh)
#pragma unroll
      for (int e = 0; e < 16; ++e) s[kh][e] = 0.f;
    __builtin_amdgcn_s_setprio(1);
#pragma unroll
    for (int ds = 0; ds < 4; ++ds)
#pragma unroll
      for (int kh = 0; kh < 2; ++kh)
        s[kh] = __builtin_amdgcn_mfma_f32_32x32x16_bf16(kf[kh][ds], qf[ds],
                                                        s[kh], 0, 0, 0);
    __builtin_amdgcn_s_setprio(0);

    // ---- V fragments issued early: latency hides under softmax ----
    bf16x8 vf[2][4];
#pragma unroll
    for (int dh = 0; dh < 2; ++dh) {
      const int vrow = dh * 32 + q32;  // vrow&7 == l7
#pragma unroll
      for (int ks = 0; ks < 4; ++ks)
        vf[dh][ks] = __builtin_bit_cast(
            bf16x8,
            *(const u16x8*)&Vl[buf][vrow * 64 + (((ks * 2 + h) ^ l7) * 8)]);
    }

    // ---- causal mask (diagonal tile only) ----
    if (it == ntiles - 1) {
#pragma unroll
      for (int kh = 0; kh < 2; ++kh)
#pragma unroll
        for (int reg = 0; reg < 16; ++reg) {
          const int key = kt + kh * 32 + (reg & 3) + 8 * (reg >> 2) + 4 * h;
          if (key > qglob) s[kh][reg] = -1e30f;
        }
    }

    // ---- softmax: lane-local max over own 32 keys + 1 swap ----
    float tm = s[0][0];
#pragma unroll
    for (int kh = 0; kh < 2; ++kh)
#pragma unroll
      for (int reg = 0; reg < 16; ++reg)
        if (kh + reg) tm = fmaxf(tm, s[kh][reg]);  // chain -> v_max3
    tm = fmaxf(tm, __shfl_xor(tm, 32, 64));        // partner has same q
    const float pm = tm * SC;
    if (!__all(pm <= mrow + 4.f)) {  // defer-max (T13)
      const float mn = fmaxf(mrow, pm);
      const float al = EXP2(mrow - mn);
      mrow = mn;
      lsum *= al;
#pragma unroll
      for (int t = 0; t < 2; ++t)
#pragma unroll
        for (int e = 0; e < 16; ++e) Oacc[t][e] *= al;
    }

    // ---- exp + in-register bf16 pack: pr0 = keys (c0,c1), pr1 = (c2,c3)
    //      of key = c + 8m + 4h  (reg = c + 4m) ----
    u32 pr0[2][4], pr1[2][4];
    float ls = 0.f;
#pragma unroll
    for (int kh = 0; kh < 2; ++kh)
#pragma unroll
      for (int m = 0; m < 4; ++m) {
        const float p0 = EXP2(__builtin_fmaf(s[kh][4 * m + 0], SC, -mrow));
        const float p1 = EXP2(__builtin_fmaf(s[kh][4 * m + 1], SC, -mrow));
        const float p2 = EXP2(__builtin_fmaf(s[kh][4 * m + 2], SC, -mrow));
        const float p3 = EXP2(__builtin_fmaf(s[kh][4 * m + 3], SC, -mrow));
        ls += (p0 + p1) + (p2 + p3);
        pr0[kh][m] = pk2(p0, p1);
        pr1[kh][m] = pk2(p2, p3);
      }
    lsum += ls;

    // ---- O^T += V^T P^T: B-frags assembled via 2 shfl per key-slice ----
    __builtin_amdgcn_s_setprio(1);
#pragma unroll
    for (int ks = 0; ks < 4; ++ks) {
      const int kh = ks >> 1, k2 = ks & 1;
      const u32 snd0 = h ? pr0[kh][2 * k2] : pr0[kh][2 * k2 + 1];
      const u32 snd1 = h ? pr1[kh][2 * k2] : pr1[kh][2 * k2 + 1];
      const u32 rc0 = (u32)__shfl_xor((int)snd0, 32, 64);
      const u32 rc1 = (u32)__shfl_xor((int)snd1, 32, 64);
      const u32 ow0 = h ? pr0[kh][2 * k2 + 1] : pr0[kh][2 * k2];
      const u32 ow1 = h ? pr1[kh][2 * k2 + 1] : pr1[kh][2 * k2];
      u32x4 fr;
      fr[0] = h ? rc0 : ow0;
      fr[1] = h ? rc1 : ow1;
      fr[2] = h ? ow0 : rc0;
      fr[3] = h ? ow1 : rc1;
      const bf16x8 pb = __builtin_bit_cast(bf16x8, fr);
      Oacc[0] = __builtin_amdgcn_mfma_f32_32x32x16_bf16(vf[0][ks], pb, Oacc[0],
                                                        0, 0, 0);
      Oacc[1] = __builtin_amdgcn_mfma_f32_32x32x16_bf16(vf[1][ks], pb, Oacc[1],
                                                        0, 0, 0);
    }
    __builtin_amdgcn_s_setprio(0);
    __syncthreads();  // buf consumed; next iter may overwrite it
  }

  // ---- epilogue: merge l across key-halves, normalize, write O^T ----
  const float lt = lsum + __shfl_xor(lsum, 32, 64);
  const float invl = 1.f / lt;
#pragma unroll
  for (int dh = 0; dh < 2; ++dh)
#pragma unroll
    for (int rg = 0; rg < 4; ++rg) {
      u16x4 pk;
#pragma unroll
      for (int cc = 0; cc < 4; ++cc)
        pk[cc] = cvt_bf16(Oacc[dh][rg * 4 + cc] * invl);
      *(u16x4*)&Qy[(bh * SEQ + qglob) * HEAD_DIM + dh * 32 + rg * 8 + 4 * h] =
          pk;
    }
}

// ======== launch ========
extern "C" void kernel_launch(void* const* d_in, const int* in_sizes, int n_in,
                              void* d_out, int out_size, void* d_ws,
                              size_t ws_size, hipStream_t stream) {
  const float* x = (const float*)d_in[0];
  const float* w_attn = (const float*)d_in[1];
  const float* b_attn = (const float*)d_in[2];
  const float* w_proj = (const float*)d_in[3];
  const float* b_proj = (const float*)d_in[4];
  float* out = (float*)d_out;

  // ws: q 8 | k 8 | vT 8 | wT_a 6 | wT_p 2 | xb 8  = 40 MB
  char* ws = (char*)d_ws;
  const size_t SZ = (size_t)BATCH * N_HEAD * SEQ * HEAD_DIM * sizeof(u16);
  u16* q = (u16*)(ws);
  u16* k = (u16*)(ws + SZ);
  u16* vT = (u16*)(ws + 2 * SZ);
  u16* wT_a = (u16*)(ws + 3 * SZ);
  u16* wT_p = (u16*)(ws + 3 * SZ + (size_t)3 * N_EMBD * N_EMBD * sizeof(u16));
  u16* xb = (u16*)(ws + 3 * SZ + (size_t)4 * N_EMBD * N_EMBD * sizeof(u16));

  prep<<<2048 + 4096, 256, 0, stream>>>(x, xb, w_attn, w_proj, wT_a, wT_p);

  gemm_qkv<<<dim3(3 * N_EMBD / 192, M_ROWS / 128), 512,
             (2 * 128 * 64 + 2 * 192 * 64) * sizeof(u16), stream>>>(
      xb, wT_a, b_attn, q, k, vT);

  flash_attn<<<NQT * 32, 128, 0, stream>>>(q, k, vT);

  gemm_proj<<<dim3(N_EMBD / 64, M_ROWS / 128), 256, 0, stream>>>(
      q, wT_p, b_proj, out);
}

// Round 13
// 171.575 us; speedup vs baseline: 1.0746x; 1.0746x over previous
//
#include <hip/hip_runtime.h>

typedef unsigned short u16;
typedef u16 u16x4 __attribute__((ext_vector_type(4)));
typedef u16 u16x8 __attribute__((ext_vector_type(8)));
typedef __bf16 bf16x8 __attribute__((ext_vector_type(8)));
typedef float floatx4 __attribute__((ext_vector_type(4)));

#define N_EMBD 1024
#define N_HEAD 16
#define HEAD_DIM 64
#define SEQ 2048
#define BATCH 2
#define M_ROWS (BATCH * SEQ)  // 4096

typedef __attribute__((address_space(1))) const unsigned char ga_t;
typedef __attribute__((address_space(3))) unsigned char la_t;

#if __has_builtin(__builtin_amdgcn_exp2f)
#define EXP2(x) __builtin_amdgcn_exp2f(x)
#else
#define EXP2(x) exp2f(x)
#endif

// native gfx950 f32->bf16 (RNE), 1 instr
__device__ __forceinline__ u16 cvt_bf16(float f) {
  return __builtin_bit_cast(u16, (__bf16)f);
}

// ======== prep: convert x (blocks 0..2047) + transpose both weights ========
// Transpose now 64x64 tiles (was 32x32): float4 loads (256B/row-segment),
// LDS pitch 68 u16 (read phase: 16 or-slots x 8B -> 32 distinct banks),
// u16x4 writes -> 128B contiguous per output row, 4x fewer blocks.
__global__ __launch_bounds__(256) void prep(const float* __restrict__ x,
                                            u16* __restrict__ xb,
                                            const float* __restrict__ wa,
                                            const float* __restrict__ wp,
                                            u16* __restrict__ outa,
                                            u16* __restrict__ outp) {
  const int bid = blockIdx.x;
  if (bid < 2048) {  // convert_x
    const long i = ((long)bid * 256 + threadIdx.x) * 8;
    const float4 f0 = *(const float4*)&x[i];
    const float4 f1 = *(const float4*)&x[i + 4];
    u16x8 p;
    p[0] = cvt_bf16(f0.x); p[1] = cvt_bf16(f0.y);
    p[2] = cvt_bf16(f0.z); p[3] = cvt_bf16(f0.w);
    p[4] = cvt_bf16(f1.x); p[5] = cvt_bf16(f1.y);
    p[6] = cvt_bf16(f1.z); p[7] = cvt_bf16(f1.w);
    *(u16x8*)&xb[i] = p;
    return;
  }
  // transpose: 64x64 tiles. t<768: w_attn (48x16 tiles); else w_proj (16x16)
  __shared__ u16 tile[64][68];
  const int t = bid - 2048;
  const float* in;
  u16* out;
  int C, bx, by;
  if (t < 768) {
    in = wa; out = outa; C = 3 * N_EMBD;
    bx = (t % 48) * 64; by = (t / 48) * 64;
  } else {
    const int t2 = t - 768;
    in = wp; out = outp; C = N_EMBD;
    bx = (t2 & 15) * 64; by = (t2 >> 4) * 64;
  }
  const int r0 = threadIdx.x >> 4;        // 0..15
  const int c4 = (threadIdx.x & 15) * 4;  // 0..60
#pragma unroll
  for (int j = 0; j < 64; j += 16) {
    const float4 f = *(const float4*)&in[(long)(by + r0 + j) * C + bx + c4];
    u16x4 p;
    p[0] = cvt_bf16(f.x); p[1] = cvt_bf16(f.y);
    p[2] = cvt_bf16(f.z); p[3] = cvt_bf16(f.w);
    *(u16x4*)&tile[r0 + j][c4] = p;
  }
  __syncthreads();
  const int or4 = (threadIdx.x & 15) * 4;  // output col group (orig row)
  const int oc0 = threadIdx.x >> 4;        // output row (orig col)
#pragma unroll
  for (int j = 0; j < 64; j += 16) {
    const int oc = oc0 + j;
    u16x4 p;
#pragma unroll
    for (int k2 = 0; k2 < 4; ++k2) p[k2] = tile[or4 + k2][oc];
    *(u16x4*)&out[(long)(bx + oc) * N_EMBD + by + or4] = p;
  }
}

// ======== gemm_qkv — 128x192 tile, BK=64, 8 waves, reg-pipelined ========
// (unchanged from round 10 — verified)
#define GBK 64

__device__ __forceinline__ void stage192(const u16* __restrict__ A,
                                         const u16* __restrict__ Bt, int bm,
                                         int bn, int kt, int tid, u16* as,
                                         u16* bs) {
#pragma unroll
  for (int i = 0; i < 2; ++i) {  // A: 128 rows x 8 slots = 1024 chunks
    const int p = tid + 512 * i;
    const int row = p >> 3;              // 0..127
    const int sl = (p & 7) ^ (row & 7);  // inverse-swizzled 16B source slot
    const int wb = (i * 512 + (tid & 448)) * 8;  // wave-uniform dest (u16)
    __builtin_amdgcn_global_load_lds(
        (ga_t*)&A[(long)(bm + row) * N_EMBD + kt + sl * 8], (la_t*)&as[wb], 16,
        0, 0);
  }
#pragma unroll
  for (int i = 0; i < 3; ++i) {  // B: 192 rows x 8 slots = 1536 chunks
    const int p = tid + 512 * i;
    const int row = p >> 3;              // 0..191
    const int sl = (p & 7) ^ (row & 7);
    const int wb = (i * 512 + (tid & 448)) * 8;
    __builtin_amdgcn_global_load_lds(
        (ga_t*)&Bt[(long)(bn + row) * N_EMBD + kt + sl * 8], (la_t*)&bs[wb], 16,
        0, 0);
  }
}

__global__ __launch_bounds__(512, 4) void gemm_qkv(
    const u16* __restrict__ A, const u16* __restrict__ Bt,
    const float* __restrict__ bias, u16* __restrict__ qo, u16* __restrict__ ko,
    u16* __restrict__ vo) {
  extern __shared__ u16 smem[];
  u16* As = smem;                 // [2][128*64]
  u16* Bs = smem + 2 * 128 * 64;  // [2][192*64]
  const int tid = threadIdx.x;

  // bijective XCD swizzle (nwg = 512)
  const int nx = gridDim.x;  // 16
  const int nwg = nx * gridDim.y;
  int lin = blockIdx.y * nx + blockIdx.x;
  lin = (lin & 7) * (nwg >> 3) + (lin >> 3);
  const int bm = (lin / nx) * 128;
  const int bn = (lin % nx) * 192;

  const int w = tid >> 6;        // 0..7
  const int l = tid & 63;
  const int wm = (w >> 2) * 64;  // 2 M-rows of waves
  const int wn = (w & 3) * 48;   // 4 N-cols of waves (48 = mult of 16)
  const int m16 = l & 15;
  const int quad = l >> 4;
  const int rsw = m16 & 7;  // read-side XOR (frag row&7 == m16&7)

  floatx4 acc[4][3];
#pragma unroll
  for (int i = 0; i < 4; ++i)
#pragma unroll
    for (int j = 0; j < 3; ++j) acc[i][j] = (floatx4){0.f, 0.f, 0.f, 0.f};

  // prologue: tiles 0,1 in flight (5 loads each); wait tile 0
  stage192(A, Bt, bm, bn, 0, tid, As, Bs);
  stage192(A, Bt, bm, bn, GBK, tid, As + 128 * 64, Bs + 192 * 64);
  asm volatile("s_waitcnt vmcnt(5)" ::: "memory");
  __builtin_amdgcn_s_barrier();

  for (int kt = 0; kt < 16; ++kt) {
    u16* as = As + (kt & 1) * (128 * 64);
    u16* bs = Bs + (kt & 1) * (192 * 64);

    // all fragments of tile kt -> registers (14 x ds_read_b128)
    bf16x8 af[4][2], bf[3][2];
#pragma unroll
    for (int i = 0; i < 4; ++i)
#pragma unroll
      for (int kk = 0; kk < 2; ++kk)
        af[i][kk] = __builtin_bit_cast(
            bf16x8, *(const u16x8*)&as[(wm + i * 16 + m16) * 64 +
                                       (((kk * 4 + quad) ^ rsw) * 8)]);
#pragma unroll
    for (int j = 0; j < 3; ++j)
#pragma unroll
      for (int kk = 0; kk < 2; ++kk)
        bf[j][kk] = __builtin_bit_cast(
            bf16x8, *(const u16x8*)&bs[(wn + j * 16 + m16) * 64 +
                                       (((kk * 4 + quad) ^ rsw) * 8)]);
    asm volatile("s_waitcnt lgkmcnt(0)" ::: "memory");
    __builtin_amdgcn_s_barrier();  // all waves done READING this buffer

    if (kt + 2 < 16) {
      stage192(A, Bt, bm, bn, (kt + 2) * GBK, tid, as, bs);  // freed buffer
      asm volatile("s_waitcnt vmcnt(5)" ::: "memory");  // own kt+1 loads done
    } else {
      asm volatile("s_waitcnt vmcnt(0)" ::: "memory");
    }
    __builtin_amdgcn_s_barrier();  // tile kt+1 visible to every wave

    __builtin_amdgcn_s_setprio(1);
#pragma unroll
    for (int kk = 0; kk < 2; ++kk)  // kk outermost: no dependent MFMA pairs
#pragma unroll
      for (int i = 0; i < 4; ++i)
#pragma unroll
        for (int j = 0; j < 3; ++j)
          acc[i][j] = __builtin_amdgcn_mfma_f32_16x16x32_bf16(
              af[i][kk], bf[j][kk], acc[i][j], 0, 0, 0);
    __builtin_amdgcn_s_setprio(0);
  }

  // epilogue: scatter q/k (bf16 [B,H,T,D]) and vT ([B,H,D,T])
#pragma unroll
  for (int i = 0; i < 4; ++i) {
#pragma unroll
    for (int j = 0; j < 3; ++j) {
      const int col = bn + wn + j * 16 + m16;
      const float bv = bias[col];
      const int which = col >> 10;  // 0=q 1=k 2=v (uniform: 16-col frag
      const int cc = col & 1023;    //  is 16-aligned, never crosses 64)
      const int h = cc >> 6;
      const int dd = cc & 63;
      const int row0 = bm + wm + i * 16 + quad * 4;
      const int b = row0 >> 11;
      const int t0 = row0 & 2047;
      if (which == 2) {
        u16x4 pk;
#pragma unroll
        for (int r = 0; r < 4; ++r) pk[r] = cvt_bf16(acc[i][j][r] + bv);
        *(u16x4*)&vo[(((long)(b * N_HEAD + h)) * HEAD_DIM + dd) * SEQ + t0] =
            pk;
      } else {
        u16* dst = (which == 0) ? qo : ko;
#pragma unroll
        for (int r = 0; r < 4; ++r)
          dst[(((long)(b * N_HEAD + h)) * SEQ + t0 + r) * HEAD_DIM + dd] =
              cvt_bf16(acc[i][j][r] + bv);
      }
    }
  }
}

// ======== gemm_proj — 128x64 tile, BK=64, 4 waves, reg-pipelined ========
// (unchanged from round 11 — verified)
#define PBK 64

__device__ __forceinline__ void stage_proj(const u16* __restrict__ A,
                                           const u16* __restrict__ Bt, int bm,
                                           int bn, int kt, int tid, u16* as,
                                           u16* bs) {
  const int head = kt >> 6;  // kt is a multiple of 64
#pragma unroll
  for (int i = 0; i < 4; ++i) {  // A: 128 rows x 8 slots = 1024 chunks
    const int p = tid + 256 * i;
    const int row = p >> 3;              // 0..127
    const int sl = (p & 7) ^ (row & 7);  // inverse-swizzled 16B source slot
    const int wb = (i * 256 + (tid & 192)) * 8;  // wave-uniform dest (u16)
    const int m = bm + row;
    const int b = m >> 11, t = m & 2047;
    __builtin_amdgcn_global_load_lds(
        (ga_t*)&A[(((long)(b * N_HEAD + head)) * SEQ + t) * HEAD_DIM + sl * 8],
        (la_t*)&as[wb], 16, 0, 0);
  }
#pragma unroll
  for (int i = 0; i < 2; ++i) {  // B: 64 rows x 8 slots = 512 chunks
    const int p = tid + 256 * i;
    const int row = p >> 3;  // 0..63
    const int sl = (p & 7) ^ (row & 7);
    const int wb = (i * 256 + (tid & 192)) * 8;
    __builtin_amdgcn_global_load_lds(
        (ga_t*)&Bt[(long)(bn + row) * N_EMBD + kt + sl * 8], (la_t*)&bs[wb], 16,
        0, 0);
  }
}

__global__ __launch_bounds__(256) void gemm_proj(const u16* __restrict__ A,
                                                 const u16* __restrict__ Bt,
                                                 const float* __restrict__ bias,
                                                 float* __restrict__ out) {
  __shared__ u16 As[2][128 * 64];  // 32 KB
  __shared__ u16 Bs[2][64 * 64];   // 16 KB
  const int tid = threadIdx.x;

  // bijective XCD swizzle (nwg = 512)
  const int nx = gridDim.x;  // 16
  const int nwg = nx * gridDim.y;
  int lin = blockIdx.y * nx + blockIdx.x;
  lin = (lin & 7) * (nwg >> 3) + (lin >> 3);
  const int bm = (lin / nx) * 128;
  const int bn = (lin % nx) * 64;

  const int w = tid >> 6;        // 0..3
  const int l = tid & 63;
  const int wm = (w >> 1) * 64;  // {0,64}
  const int wn = (w & 1) * 32;   // {0,32}
  const int m16 = l & 15;
  const int quad = l >> 4;
  const int rsw = m16 & 7;

  floatx4 acc[4][2];
#pragma unroll
  for (int i = 0; i < 4; ++i)
#pragma unroll
    for (int j = 0; j < 2; ++j) acc[i][j] = (floatx4){0.f, 0.f, 0.f, 0.f};

  // prologue: tiles 0,1 in flight (6 loads each); wait tile 0
  stage_proj(A, Bt, bm, bn, 0, tid, As[0], Bs[0]);
  stage_proj(A, Bt, bm, bn, PBK, tid, As[1], Bs[1]);
  asm volatile("s_waitcnt vmcnt(6)" ::: "memory");
  __builtin_amdgcn_s_barrier();

  for (int kt = 0; kt < 16; ++kt) {
    u16* as = As[kt & 1];
    u16* bs = Bs[kt & 1];

    bf16x8 af[4][2], bf[2][2];
#pragma unroll
    for (int i = 0; i < 4; ++i)
#pragma unroll
      for (int kk = 0; kk < 2; ++kk)
        af[i][kk] = __builtin_bit_cast(
            bf16x8, *(const u16x8*)&as[(wm + i * 16 + m16) * 64 +
                                       (((kk * 4 + quad) ^ rsw) * 8)]);
#pragma unroll
    for (int j = 0; j < 2; ++j)
#pragma unroll
      for (int kk = 0; kk < 2; ++kk)
        bf[j][kk] = __builtin_bit_cast(
            bf16x8, *(const u16x8*)&bs[(wn + j * 16 + m16) * 64 +
                                       (((kk * 4 + quad) ^ rsw) * 8)]);
    asm volatile("s_waitcnt lgkmcnt(0)" ::: "memory");
    __builtin_amdgcn_s_barrier();  // all waves done READING this buffer

    if (kt + 2 < 16) {
      stage_proj(A, Bt, bm, bn, (kt + 2) * PBK, tid, as, bs);
      asm volatile("s_waitcnt vmcnt(6)" ::: "memory");  // own kt+1 loads done
    } else {
      asm volatile("s_waitcnt vmcnt(0)" ::: "memory");
    }
    __builtin_amdgcn_s_barrier();  // tile kt+1 visible to every wave

    __builtin_amdgcn_s_setprio(1);
#pragma unroll
    for (int kk = 0; kk < 2; ++kk)
#pragma unroll
      for (int i = 0; i < 4; ++i)
#pragma unroll
        for (int j = 0; j < 2; ++j)
          acc[i][j] = __builtin_amdgcn_mfma_f32_16x16x32_bf16(
              af[i][kk], bf[j][kk], acc[i][j], 0, 0, 0);
    __builtin_amdgcn_s_setprio(0);
  }

  // epilogue: fp32 out + bias
#pragma unroll
  for (int i = 0; i < 4; ++i) {
#pragma unroll
    for (int j = 0; j < 2; ++j) {
      const int col = bn + wn + j * 16 + m16;
      const float bv = bias[col];
#pragma unroll
      for (int r = 0; r < 4; ++r) {
        const int row = bm + wm + i * 16 + quad * 4 + r;
        out[(long)row * N_EMBD + col] = acc[i][j][r] + bv;
      }
    }
  }
}

// ======== flash attention — round-11 verified (balanced CU schedule) ======
// 1024 blocks (32 q-tiles x 32 bh), 256 threads, LDS 40960 B -> exactly
// 4 blocks/CU. Map id=(r*256+c), g=c>>5, bh=c&31: iq = {31-g,16+g,15-g,g}[r]
// -> every CU's four co-resident blocks total 66 tile-iters (balanced).
// id%8 = bh%8 keeps each head's KV on one XCD's L2. Measured 42.8 us.
// [r12 lesson: 4-wave x 4-block balance beats shorter chains — 128-thread
//  32x32 swapped variant ran 59 us at 13% occupancy despite fewer ops.]
#define BQ 64
#define BKV 64
#define LOG2E 1.44269504f
#define NQT (SEQ / BQ)  // 32 q-tiles

__device__ __forceinline__ void stage_kv(const u16* __restrict__ K,
                                         const u16* __restrict__ Vt, long bh,
                                         int kt, int tid, u16* kl, u16* vl) {
#pragma unroll
  for (int i = 0; i < 2; ++i) {
    const int p = tid + 256 * i;
    const int row = p >> 3;                    // K: key   V: d
    const int slot = (p & 7) ^ (row & 7);      // swizzled 16B source slot
    const int wb = (i * 256 + (tid & 192)) * 8;  // wave-uniform dest (u16)
    __builtin_amdgcn_global_load_lds(
        (ga_t*)&K[(bh * SEQ + kt + row) * HEAD_DIM + slot * 8], (la_t*)&kl[wb],
        16, 0, 0);
    __builtin_amdgcn_global_load_lds(
        (ga_t*)&Vt[(bh * HEAD_DIM + row) * SEQ + kt + slot * 8], (la_t*)&vl[wb],
        16, 0, 0);
  }
}

__global__ __launch_bounds__(256, 4) void flash_attn(
    u16* __restrict__ Qy, const u16* __restrict__ K,
    const u16* __restrict__ Vt) {
  const int id = blockIdx.x;
  const int r = id >> 8;  // 0..3  (co-CU class = id & 255)
  const int c = id & 255;
  const int g = c >> 5;   // 0..7
  const long bh = c & 31;
  const int iq = (r == 0) ? (31 - g)
               : (r == 1) ? (16 + g)
               : (r == 2) ? (15 - g)
                          : g;
  const int tid = threadIdx.x;
  const int w = tid >> 6;
  const int l = tid & 63;
  const int m16 = l & 15;
  const int quad = l >> 4;

  __shared__ u16 Kl[2][BKV * 64];  // [buf][key][d]  linear, swizzled source
  __shared__ u16 Vl[2][64 * BKV];  // [buf][d][key]  linear, swizzled source
  __shared__ u16 Pl[4][16 * 64];   // per-wave [q][key], XOR-swizzled cols

  const float SC = 0.125f * LOG2E;
  const int qb = iq * BQ;
  const int ntiles = iq + 1;
  const int qglob = qb + w * 16 + m16;
  const int sw = (m16 & 7) << 3;  // u16-col XOR for reads of row (..16+m16)

  bf16x8 qf[2];
  {
    const u16* qrow = Qy + (bh * SEQ + qglob) * HEAD_DIM;
    qf[0] = __builtin_bit_cast(bf16x8, *(const u16x8*)&qrow[quad * 8]);
    qf[1] = __builtin_bit_cast(bf16x8, *(const u16x8*)&qrow[32 + quad * 8]);
  }

  floatx4 Oacc[4];  // O^T: col=q=m16, row=d = t*16 + quad*4 + r
#pragma unroll
  for (int t = 0; t < 4; ++t) Oacc[t] = (floatx4){0.f, 0.f, 0.f, 0.f};
  float mrow = -1e30f, lsum = 0.f;  // lsum: PER-LANE partial; reduced at end

  // prologue: stage tile 0 into buf 0
  stage_kv(K, Vt, bh, 0, tid, Kl[0], Vl[0]);
  __syncthreads();

  for (int it = 0; it < ntiles; ++it) {
    const int buf = it & 1;
    const int kt = it * BKV;
    if (it + 1 < ntiles)
      stage_kv(K, Vt, bh, kt + BKV, tid, Kl[buf ^ 1], Vl[buf ^ 1]);

    // ---- S^T = K Q^T (raw scores; scale folded into exp FMA) ----
    floatx4 s[4];
#pragma unroll
    for (int j = 0; j < 4; ++j) s[j] = (floatx4){0.f, 0.f, 0.f, 0.f};
    __builtin_amdgcn_s_setprio(1);
#pragma unroll
    for (int j = 0; j < 4; ++j)
#pragma unroll
      for (int kk = 0; kk < 2; ++kk) {
        const bf16x8 kf = __builtin_bit_cast(
            bf16x8, *(const u16x8*)&Kl[buf][(j * 16 + m16) * 64 +
                                            ((kk * 32 + quad * 8) ^ sw)]);
        s[j] = __builtin_amdgcn_mfma_f32_16x16x32_bf16(kf, qf[kk], s[j], 0, 0,
                                                       0);
      }
    __builtin_amdgcn_s_setprio(0);
    if (it == ntiles - 1) {
#pragma unroll
      for (int j = 0; j < 4; ++j) {
        const int key0 = kt + j * 16 + quad * 4;
#pragma unroll
        for (int r = 0; r < 4; ++r)
          if (key0 + r > qglob) s[j][r] = -1e30f;
      }
    }

    // ---- online softmax with defer-max (T13) ----
    float tm = s[0][0];
#pragma unroll
    for (int j = 0; j < 4; ++j)
#pragma unroll
      for (int r = 0; r < 4; ++r)
        if (j + r) tm = fmaxf(tm, s[j][r]);  // linear chain -> v_max3
    tm = fmaxf(tm, __shfl_xor(tm, 16, 64));
    tm = fmaxf(tm, __shfl_xor(tm, 32, 64));
    const float pm = tm * SC;
    if (!__all(pm <= mrow + 4.f)) {
      const float mn = fmaxf(mrow, pm);
      const float al = EXP2(mrow - mn);
      mrow = mn;
      lsum *= al;  // per-lane partial rescales identically (al row-uniform)
#pragma unroll
      for (int t = 0; t < 4; ++t)
#pragma unroll
        for (int r = 0; r < 4; ++r) Oacc[t][r] *= al;
    }

    float ls = 0.f;
#pragma unroll
    for (int j = 0; j < 4; ++j) {
      u16x4 pk;
#pragma unroll
      for (int r = 0; r < 4; ++r) {
        const float p = EXP2(__builtin_fmaf(s[j][r], SC, -mrow));
        ls += p;
        pk[r] = cvt_bf16(p);
      }
      *(u16x4*)&Pl[w][m16 * 64 + ((j * 16 + quad * 4) ^ sw)] = pk;
    }
    lsum += ls;  // cross-lane reduction deferred to epilogue

    // ---- O^T += V^T P^T (both from LDS, swizzled reads) ----
    bf16x8 pf[2];
    pf[0] = __builtin_bit_cast(
        bf16x8, *(const u16x8*)&Pl[w][m16 * 64 + ((quad * 8) ^ sw)]);
    pf[1] = __builtin_bit_cast(
        bf16x8, *(const u16x8*)&Pl[w][m16 * 64 + ((32 + quad * 8) ^ sw)]);
    __builtin_amdgcn_s_setprio(1);
#pragma unroll
    for (int t = 0; t < 4; ++t)
#pragma unroll
      for (int kk = 0; kk < 2; ++kk) {
        const bf16x8 vf = __builtin_bit_cast(
            bf16x8, *(const u16x8*)&Vl[buf][(t * 16 + m16) * 64 +
                                            ((kk * 32 + quad * 8) ^ sw)]);
        Oacc[t] = __builtin_amdgcn_mfma_f32_16x16x32_bf16(vf, pf[kk], Oacc[t],
                                                          0, 0, 0);
      }
    __builtin_amdgcn_s_setprio(0);
    __syncthreads();  // buf consumed; next iter may overwrite it
  }

  // ---- epilogue: reduce l across quads, then normalize + write O^T ----
  float lt = lsum;
  lt += __shfl_xor(lt, 16, 64);
  lt += __shfl_xor(lt, 32, 64);
  const float invl = 1.f / lt;
#pragma unroll
  for (int t = 0; t < 4; ++t) {
    u16x4 pk;
#pragma unroll
    for (int r = 0; r < 4; ++r) pk[r] = cvt_bf16(Oacc[t][r] * invl);
    *(u16x4*)&Qy[(bh * SEQ + qglob) * HEAD_DIM + t * 16 + quad * 4] = pk;
  }
}

// ======== launch ========
extern "C" void kernel_launch(void* const* d_in, const int* in_sizes, int n_in,
                              void* d_out, int out_size, void* d_ws,
                              size_t ws_size, hipStream_t stream) {
  const float* x = (const float*)d_in[0];
  const float* w_attn = (const float*)d_in[1];
  const float* b_attn = (const float*)d_in[2];
  const float* w_proj = (const float*)d_in[3];
  const float* b_proj = (const float*)d_in[4];
  float* out = (float*)d_out;

  // ws: q 8 | k 8 | vT 8 | wT_a 6 | wT_p 2 | xb 8  = 40 MB
  char* ws = (char*)d_ws;
  const size_t SZ = (size_t)BATCH * N_HEAD * SEQ * HEAD_DIM * sizeof(u16);
  u16* q = (u16*)(ws);
  u16* k = (u16*)(ws + SZ);
  u16* vT = (u16*)(ws + 2 * SZ);
  u16* wT_a = (u16*)(ws + 3 * SZ);
  u16* wT_p = (u16*)(ws + 3 * SZ + (size_t)3 * N_EMBD * N_EMBD * sizeof(u16));
  u16* xb = (u16*)(ws + 3 * SZ + (size_t)4 * N_EMBD * N_EMBD * sizeof(u16));

  prep<<<2048 + 1024, 256, 0, stream>>>(x, xb, w_attn, w_proj, wT_a, wT_p);

  gemm_qkv<<<dim3(3 * N_EMBD / 192, M_ROWS / 128), 512,
             (2 * 128 * 64 + 2 * 192 * 64) * sizeof(u16), stream>>>(
      xb, wT_a, b_attn, q, k, vT);

  flash_attn<<<NQT * 32, 256, 0, stream>>>(q, k, vT);

  gemm_proj<<<dim3(N_EMBD / 64, M_ROWS / 128), 256, 0, stream>>>(
      q, wT_p, b_proj, out);
}